// Round 1
// baseline (408.450 us; speedup 1.0000x reference)
//
#include <hip/hip_runtime.h>

// UpSampling3D: x [2,32,48,48,48] f32 -> y [2,32,96,96,96] f32
// Separable linear interp, align_corners=True, scale 2 per axis.
// Per-axis positions: xx(o) = 47*o/95; weights (1-frac, frac) on (floor, floor+1),
// normalized by 1/(1+1e-6) per axis (three axes -> norm^3).

#define IN_N      48
#define OUT_N     96
#define IN_SLICE  (48*48*48)    // 110592
#define NB_H      64            // 2*32
#define TOTAL4    (NB_H*96*96*24) // 14155776 float4 outputs

__device__ __forceinline__ void axis_w(int o, int& i0, int& i1, float& w0, float& w1) {
    float xx = (float)(47 * o) / 95.0f;
    float f  = floorf(xx);
    int  fi  = (int)f;
    float fr = xx - f;
    i0 = fi;
    i1 = min(fi + 1, IN_N - 1);
    w1 = fr;
    w0 = 1.0f - fr;
}

__global__ __launch_bounds__(256) void up3d_kernel(const float* __restrict__ x,
                                                   float* __restrict__ y) {
    int t = blockIdx.x * blockDim.x + threadIdx.x;
    if (t >= TOTAL4) return;

    int d4  = t % 24;          // which group of 4 outputs along D
    int tmp = t / 24;
    int c   = tmp % 96;
    tmp    /= 96;
    int r   = tmp % 96;
    int bh  = tmp / 96;        // [0,64)

    int r0, r1, c0, c1;
    float wr0, wr1, wc0, wc1;
    axis_w(r, r0, r1, wr0, wr1);
    axis_w(c, c0, c1, wc0, wc1);

    const float* base = x + (size_t)bh * IN_SLICE;
    const float* p00 = base + r0 * (IN_N * IN_N) + c0 * IN_N;
    const float* p01 = base + r0 * (IN_N * IN_N) + c1 * IN_N;
    const float* p10 = base + r1 * (IN_N * IN_N) + c0 * IN_N;
    const float* p11 = base + r1 * (IN_N * IN_N) + c1 * IN_N;

    const float w00 = wr0 * wc0, w01 = wr0 * wc1;
    const float w10 = wr1 * wc0, w11 = wr1 * wc1;

    // per-axis 1/(1+1e-6), cubed
    const float norm = 1.0f / ((1.0f + 1e-6f) * (1.0f + 1e-6f) * (1.0f + 1e-6f));

    float4 out;
    float* o = reinterpret_cast<float*>(&out);
    #pragma unroll
    for (int k = 0; k < 4; ++k) {
        int dd = d4 * 4 + k;
        int d0, d1; float wd0, wd1;
        axis_w(dd, d0, d1, wd0, wd1);
        float v00 = wd0 * p00[d0] + wd1 * p00[d1];
        float v01 = wd0 * p01[d0] + wd1 * p01[d1];
        float v10 = wd0 * p10[d0] + wd1 * p10[d1];
        float v11 = wd0 * p11[d0] + wd1 * p11[d1];
        o[k] = (w00 * v00 + w01 * v01 + w10 * v10 + w11 * v11) * norm;
    }
    reinterpret_cast<float4*>(y)[t] = out;
}

extern "C" void kernel_launch(void* const* d_in, const int* in_sizes, int n_in,
                              void* d_out, int out_size, void* d_ws, size_t ws_size,
                              hipStream_t stream) {
    const float* x = (const float*)d_in[0];
    float* y = (float*)d_out;
    const int blocks = TOTAL4 / 256;  // 55296, exact
    hipLaunchKernelGGL(up3d_kernel, dim3(blocks), dim3(256), 0, stream, x, y);
}

// Round 2
// 255.296 us; speedup vs baseline: 1.5999x; 1.5999x over previous
//
#include <hip/hip_runtime.h>

// UpSampling3D x2 trilinear, align_corners=True.
// x [64,48,48,48] f32 -> y [64,96,96,96] f32  (64 = 2*32 batch*chan)
// Per-axis: pos(o) = 47*o/95; w = (1-fr, fr) at (floor, floor+1); norm 1/(1+1e-6) per axis.
//
// Structure: block = 16x16 (r_out,c_out) tile, one full 96-d line per thread.
//  A) stage input tile [10][10][48] -> LDS (row-pad 52), coalesced float4
//  B) per 32-d chunk: read 4 rows as b128 windows from LDS; fully-unrolled
//     compile-time d-structure (d0/frac constexpr) -> all reg indices static
//  C) transpose result through LDS (pad 36) -> contiguous float4 global stores

#define IN_N   48
#define OUT_N  96
#define RS_IN  (48*48)
#define BH_IN  (48*48*48)
#define RS_OUT (96*96)
#define BH_OUT (96*96*96)

#define TR 16
#define TC 16
#define NROW 10
#define LDS_ROWP 52   // padded d-stride of input tile rows (bank spread, 16B-aligned)
#define RES_P 36      // padded stride of 32-float result rows (16B-aligned)

__device__ __forceinline__ constexpr int d0_of(int o) { return (47 * o) / 95; }

__global__ __launch_bounds__(256) void up3d_kernel(const float* __restrict__ x,
                                                   float* __restrict__ y) {
    __shared__ float lds_in[NROW * NROW * LDS_ROWP]; // 5200 f = 20.8 KB
    __shared__ float res[TR * TC * RES_P];           // 9216 f = 36.9 KB

    const int tid = threadIdx.x;
    const int bc = blockIdx.x, br = blockIdx.y, bh = blockIdx.z;

    const int rlo = (47 * (TR * br)) / 95;
    const int clo = (47 * (TC * bc)) / 95;

    // ---- stage A: input tile -> LDS ----
    const float* xb = x + (size_t)bh * BH_IN;
    for (int i = tid; i < NROW * NROW * 12; i += 256) {
        int row = i / 12, k = i % 12;
        int ri = row / NROW, ci = row % NROW;
        int gr = min(rlo + ri, IN_N - 1);
        int gc = min(clo + ci, IN_N - 1);
        float4 v = *reinterpret_cast<const float4*>(xb + gr * RS_IN + gc * IN_N + 4 * k);
        *reinterpret_cast<float4*>(&lds_in[row * LDS_ROWP + 4 * k]) = v;
    }
    __syncthreads();

    // ---- per-thread output line setup ----
    const int r_loc = tid / TC, c_loc = tid % TC;
    const int r_out = TR * br + r_loc;
    const int c_out = TC * bc + c_loc;

    const int r0 = (47 * r_out) / 95;
    const int r1 = min(r0 + 1, IN_N - 1);
    const float wr1 = (float)((47 * r_out) % 95) / 95.0f;
    const float wr0 = 1.0f - wr1;
    const int c0 = (47 * c_out) / 95;
    const int c1 = min(c0 + 1, IN_N - 1);
    const float wc1 = (float)((47 * c_out) % 95) / 95.0f;
    const float wc0 = 1.0f - wc1;

    const int row00 = ((r0 - rlo) * NROW + (c0 - clo)) * LDS_ROWP;
    const int row01 = ((r0 - rlo) * NROW + (c1 - clo)) * LDS_ROWP;
    const int row10 = ((r1 - rlo) * NROW + (c0 - clo)) * LDS_ROWP;
    const int row11 = ((r1 - rlo) * NROW + (c1 - clo)) * LDS_ROWP;

    const float n1 = 1.0f / (1.0f + 1e-6f);
    const float norm = n1 * n1 * n1;

    float* yb = y + (size_t)bh * BH_OUT;

    // d-chunk windows (floats, compile-time): chunk ch covers dd in [32ch, 32ch+32)
    constexpr int WBASE[3] = {0, 12, 28};
    constexpr int NW[3]    = {5, 6, 5};

    #pragma unroll
    for (int ch = 0; ch < 3; ++ch) {
        float acc[32];

        // pass 1: rows (r0,c0),(r0,c1)
        {
            float a[24], b[24];
            #pragma unroll
            for (int j = 0; j < 6; ++j) {
                if (j < NW[ch]) {
                    float4 va = *reinterpret_cast<const float4*>(&lds_in[row00 + WBASE[ch] + 4 * j]);
                    float4 vb = *reinterpret_cast<const float4*>(&lds_in[row01 + WBASE[ch] + 4 * j]);
                    a[4*j+0] = va.x; a[4*j+1] = va.y; a[4*j+2] = va.z; a[4*j+3] = va.w;
                    b[4*j+0] = vb.x; b[4*j+1] = vb.y; b[4*j+2] = vb.z; b[4*j+3] = vb.w;
                }
            }
            #pragma unroll
            for (int t = 0; t < 32; ++t) {
                const int dd = ch * 32 + t;
                const int j0 = d0_of(dd) - WBASE[ch];
                const int j1 = min(d0_of(dd) + 1, IN_N - 1) - WBASE[ch];
                const float fd1 = (float)((47 * dd) % 95) / 95.0f;
                const float fd0 = 1.0f - fd1;
                float t0 = wc0 * a[j0] + wc1 * b[j0];
                float t1 = wc0 * a[j1] + wc1 * b[j1];
                acc[t] = wr0 * (fd0 * t0 + fd1 * t1);
            }
        }
        // pass 2: rows (r1,c0),(r1,c1)
        {
            float a[24], b[24];
            #pragma unroll
            for (int j = 0; j < 6; ++j) {
                if (j < NW[ch]) {
                    float4 va = *reinterpret_cast<const float4*>(&lds_in[row10 + WBASE[ch] + 4 * j]);
                    float4 vb = *reinterpret_cast<const float4*>(&lds_in[row11 + WBASE[ch] + 4 * j]);
                    a[4*j+0] = va.x; a[4*j+1] = va.y; a[4*j+2] = va.z; a[4*j+3] = va.w;
                    b[4*j+0] = vb.x; b[4*j+1] = vb.y; b[4*j+2] = vb.z; b[4*j+3] = vb.w;
                }
            }
            #pragma unroll
            for (int t = 0; t < 32; ++t) {
                const int dd = ch * 32 + t;
                const int j0 = d0_of(dd) - WBASE[ch];
                const int j1 = min(d0_of(dd) + 1, IN_N - 1) - WBASE[ch];
                const float fd1 = (float)((47 * dd) % 95) / 95.0f;
                const float fd0 = 1.0f - fd1;
                float t0 = wc0 * a[j0] + wc1 * b[j0];
                float t1 = wc0 * a[j1] + wc1 * b[j1];
                acc[t] += wr1 * (fd0 * t0 + fd1 * t1);
            }
        }

        // write result rows to LDS (transpose staging)
        #pragma unroll
        for (int q = 0; q < 8; ++q) {
            float4 v;
            v.x = acc[4*q+0] * norm;
            v.y = acc[4*q+1] * norm;
            v.z = acc[4*q+2] * norm;
            v.w = acc[4*q+3] * norm;
            *reinterpret_cast<float4*>(&res[tid * RES_P + 4 * q]) = v;
        }
        __syncthreads();

        // coalesced global store of this chunk
        #pragma unroll
        for (int it = 0; it < 8; ++it) {
            int idx = it * 256 + tid;
            int rc = idx >> 3, k = idx & 7;
            int r = rc >> 4, c = rc & 15;
            float4 v = *reinterpret_cast<const float4*>(&res[rc * RES_P + 4 * k]);
            *reinterpret_cast<float4*>(
                &yb[(size_t)(TR * br + r) * RS_OUT + (TC * bc + c) * OUT_N + ch * 32 + 4 * k]) = v;
        }
        __syncthreads();
    }
}

extern "C" void kernel_launch(void* const* d_in, const int* in_sizes, int n_in,
                              void* d_out, int out_size, void* d_ws, size_t ws_size,
                              hipStream_t stream) {
    const float* x = (const float*)d_in[0];
    float* y = (float*)d_out;
    dim3 grid(OUT_N / TC, OUT_N / TR, 64); // 6 x 6 x 64 = 2304 blocks
    hipLaunchKernelGGL(up3d_kernel, grid, dim3(256), 0, stream, x, y);
}